// Round 4
// baseline (467.280 us; speedup 1.0000x reference)
//
#include <hip/hip_runtime.h>

// UnPooling: x[32,112,112,64] f32 -> out[32,224,224,64] f32,
// out[:, ::2, ::2, :] = x, rest zero.
//
// Two-phase: (1) hipMemsetAsync zeros the whole output at the runtime fill
// kernel's ~6.35 TB/s; (2) pure gather-copy kernel moves the 103 MB of data
// into the even/even pixels. Copy kernel: one float4 per thread; loads are
// wave-contiguous (1 KB/wave); stores are 256 B chunks (16 lanes) at 512 B
// stride -> full 128 B lines only, no read-modify-write.
//
// Grid: (7, 112, 32): bx*256+tid = float4 idx j within one input row
// (112 px * 16 float4 = 1792 = 7*256); by = input row h; bz = batch b.

typedef float f4 __attribute__((ext_vector_type(4)));

__global__ __launch_bounds__(256) void unpool_copy_kernel(
    const f4* __restrict__ x, f4* __restrict__ out) {
    const int j  = blockIdx.x * 256 + threadIdx.x; // [0,1792)
    const int h  = blockIdx.y;                     // [0,112)
    const int b  = blockIdx.z;                     // [0,32)
    const int c4 = j & 15;
    const int w  = j >> 4;                         // [0,112)

    f4 v = __builtin_nontemporal_load(&x[(size_t)(b * 112 + h) * 1792 + j]);
    // out[b, 2h, 2w, c4]
    out[(size_t)(b * 224 + 2 * h) * 3584 + w * 32 + c4] = v;
}

extern "C" void kernel_launch(void* const* d_in, const int* in_sizes, int n_in,
                              void* d_out, int out_size, void* d_ws, size_t ws_size,
                              hipStream_t stream) {
    const f4* x = (const f4*)d_in[0];
    f4* out = (f4*)d_out;

    // Phase 1: zero the whole output (411 MB) at fill-kernel rate.
    hipMemsetAsync(d_out, 0, (size_t)out_size * sizeof(float), stream);

    // Phase 2: copy x into the even/even pixels.
    dim3 grid(7, 112, 32);
    dim3 block(256);
    unpool_copy_kernel<<<grid, block, 0, stream>>>(x, out);
}